// Round 7
// baseline (247.123 us; speedup 1.0000x reference)
//
#include <hip/hip_runtime.h>

#define N_NODES 10000
#define B 8
#define T_STEPS 12
#define E_EDGES 160000
#define HG 64
#define HR 64
#define P_OUT 12
#define BN (B * N_NODES)   // 80000

typedef __attribute__((ext_vector_type(8))) short short8;
typedef __attribute__((ext_vector_type(4))) float f32x4;

__device__ __forceinline__ short f2bf(float f) {
    unsigned u = __builtin_bit_cast(unsigned, f);
    u += 0x7FFFu + ((u >> 16) & 1u);     // round-to-nearest-even
    return (short)(u >> 16);
}

// pack 2 fp32 -> 2 bf16 (RNE). HW instr on gfx950 if builtin exists.
__device__ __forceinline__ unsigned pk2bf(float lo, float hi) {
#if __has_builtin(__builtin_amdgcn_cvt_pk_bf16_f32)
    typedef __attribute__((ext_vector_type(2))) __bf16 bf2;
    bf2 v = __builtin_amdgcn_cvt_pk_bf16_f32(lo, hi);
    return __builtin_bit_cast(unsigned, v);
#else
    return (unsigned)(unsigned short)f2bf(lo) |
           ((unsigned)(unsigned short)f2bf(hi) << 16);
#endif
}

// ---------------- prep: deg/cnt histogram + weight cvt (fused) ----------------

__global__ void prep_kernel(const int* __restrict__ ei, const float* __restrict__ ew,
                            float* __restrict__ deg, int* __restrict__ cnt,
                            const float* __restrict__ Wih, const float* __restrict__ Whh,
                            const float* __restrict__ Wout,
                            short* __restrict__ Wihb, short* __restrict__ Whhb,
                            short* __restrict__ Woutb) {
    if (blockIdx.x < 625) {
        int e = blockIdx.x * 256 + threadIdx.x;          // 625*256 == E_EDGES
        int d = ei[E_EDGES + e];
        atomicAdd(&deg[d], ew[e]);
        atomicAdd(&cnt[d], 1);
    } else {
        int i = (blockIdx.x - 625) * 256 + threadIdx.x;
        if (i < 192 * 64) {
            Wihb[i] = f2bf(Wih[i]);
            Whhb[i] = f2bf(Whh[i]);
        }
        if (i < 16 * 64) {
            int p = i >> 6, k = i & 63;
            Woutb[i] = (p < P_OUT) ? f2bf(Wout[p * 64 + k]) : (short)0;
        }
    }
}

// ---------------- scan (exclusive) + dinv, single block ----------------
__global__ void scan_dinv_kernel(const int* __restrict__ cnt, int* __restrict__ off,
                                 float* __restrict__ deg) {
    __shared__ int buf[10240];   // 40 KB
    __shared__ int part[256];
    const int t = threadIdx.x;
#pragma unroll 1
    for (int i = 0; i < 40; i++) {
        int idx = i * 256 + t;
        buf[idx] = (idx < N_NODES) ? cnt[idx] : 0;
    }
    __syncthreads();
    int s = 0;
#pragma unroll 1
    for (int i = 0; i < 40; i++) s += buf[t * 40 + i];
    part[t] = s;
    __syncthreads();
    for (int d = 1; d < 256; d <<= 1) {
        int v = (t >= d) ? part[t - d] : 0;
        __syncthreads();
        part[t] += v;
        __syncthreads();
    }
    int run = (t == 0) ? 0 : part[t - 1];
#pragma unroll 1
    for (int i = 0; i < 40; i++) {
        int idx = t * 40 + i;
        int c = buf[idx];
        buf[idx] = run;
        run += c;
    }
    __syncthreads();
#pragma unroll 1
    for (int i = 0; i < 40; i++) {
        int idx = i * 256 + t;
        if (idx < N_NODES) {
            off[idx] = buf[idx];
            deg[idx] = rsqrtf(deg[idx] + 1.0f);   // deg -> dinv in place
        }
    }
}

// ---------------- fill CSR (interleaved int2: src, norm-bits) ----------------
__global__ void fill_kernel(const int* __restrict__ ei, const float* __restrict__ ew,
                            const float* __restrict__ dinv, const int* __restrict__ off,
                            int* __restrict__ cursor, int2* __restrict__ csr) {
    int e = blockIdx.x * blockDim.x + threadIdx.x;
    if (e >= E_EDGES) return;
    int s = ei[e];
    int d = ei[E_EDGES + e];
    int pos = off[d] + atomicAdd(&cursor[d], 1);
    csr[pos] = make_int2(s, __float_as_int(dinv[s] * ew[e] * dinv[d]));
}

// ---------------- gather: thread per (b, n, t-quarter) ----------------
// 3x the waves of the (b,n) version (3840 vs 1250: R6's gather was occupancy-
// starved at 1.2 waves/SIMD). Each thread owns one float4 of the 12 t's.
__global__ void gather_kernel(const float* __restrict__ x, const float* __restrict__ dinv,
                              const int* __restrict__ off, const int* __restrict__ cnt,
                              const int2* __restrict__ csr, float* __restrict__ aggS) {
    int n = blockIdx.x * 256 + threadIdx.x;
    if (n >= N_NODES) return;
    const int b  = blockIdx.y;
    const int tq = blockIdx.z;
    const int fo = tq * 4;                     // float offset within the 12
    float di = dinv[n];
    float4 acc;
    {
        float4 xs = *(const float4*)&x[(b * N_NODES + n) * T_STEPS + fo];
        float w = di * di;
        acc = make_float4(w * xs.x, w * xs.y, w * xs.z, w * xs.w);
    }
    const int o0 = off[n], c = cnt[n];
    const int2* cp = &csr[o0];
#pragma unroll 4
    for (int i = 0; i < c; i++) {
        int2 pr = cp[i];
        float w = __int_as_float(pr.y);
        float4 xv = *(const float4*)&x[(b * N_NODES + pr.x) * T_STEPS + fo];
        acc.x = fmaf(w, xv.x, acc.x);
        acc.y = fmaf(w, xv.y, acc.y);
        acc.z = fmaf(w, xv.z, acc.z);
        acc.w = fmaf(w, xv.w, acc.w);
    }
    *(float4*)&aggS[(b * N_NODES + n) * T_STEPS + fo] = acc;
}

// ---------------- Fused MFMA GRU + output head ----------------

__device__ __forceinline__ float fast_rcp(float v) { return __builtin_amdgcn_rcpf(v); }
__device__ __forceinline__ float sigmoid_f(float v) { return fast_rcp(1.0f + __expf(-v)); }
__device__ __forceinline__ float tanh_f(float v) {
    float e = __expf(-2.0f * v);
    return fmaf(2.0f, fast_rcp(1.0f + e), -1.0f);
}

// Block = 64 sequences, 4 waves; wave w owns gate-units [16w,16w+16).
// vs R6: (1) double-buffered hlds/xlds by t-parity -> ONE barrier per t
// (iter t: write X into xlds[t&1], barrier, MFMA-read xlds[t&1]+hlds[t&1],
// gates write hlds[(t+1)&1]; the barrier at top of t separates iter t's
// writes from iter t-1's same-parity reads). (2) packed bf16 converts.
__global__ __launch_bounds__(256, 2) void gru_mfma_kernel(
    const float* __restrict__ aggS,
    const float* __restrict__ gW, const float* __restrict__ gb,
    const short* __restrict__ Wihb, const short* __restrict__ Whhb,
    const float* __restrict__ bih, const float* __restrict__ bhh,
    const short* __restrict__ Woutb, const float* __restrict__ bout,
    float* __restrict__ out)
{
    __shared__ short hlds[2][64 * 64];   // 16 KB
    __shared__ short xlds[2][64 * 64];   // 16 KB
    const int tid = threadIdx.x;
    const int w   = tid >> 6;
    const int wu  = __builtin_amdgcn_readfirstlane(w);
    const int l   = tid & 63;
    const int lr  = l & 15;
    const int qu  = l >> 4;
    const int blk = blockIdx.x;

    // t-invariant weight B-frags (pinned in registers)
    short8 bIr[2], bIz[2], bIn[2], bHr[2], bHz[2], bHn[2];
#pragma unroll
    for (int kt = 0; kt < 2; kt++) {
        const int ko = kt * 32 + qu * 8;
        bIr[kt] = *(const short8*)&Wihb[(      16 * wu + lr) * 64 + ko];
        bIz[kt] = *(const short8*)&Wihb[( 64 + 16 * wu + lr) * 64 + ko];
        bIn[kt] = *(const short8*)&Wihb[(128 + 16 * wu + lr) * 64 + ko];
        bHr[kt] = *(const short8*)&Whhb[(      16 * wu + lr) * 64 + ko];
        bHz[kt] = *(const short8*)&Whhb[( 64 + 16 * wu + lr) * 64 + ko];
        bHn[kt] = *(const short8*)&Whhb[(128 + 16 * wu + lr) * 64 + ko];
    }
    float gwv[16], gbv[16];
#pragma unroll
    for (int j = 0; j < 16; j++) { gwv[j] = gW[wu * 16 + j]; gbv[j] = gb[wu * 16 + j]; }

    const int u = 16 * w + lr;
    const float bR  = bih[u]       + bhh[u];
    const float bZ  = bih[u + 64]  + bhh[u + 64];
    const float bIN = bih[u + 128];
    const float bHN = bhh[u + 128];
    const int uc = u >> 3;
    const int u7 = u & 7;

    float a_all[12];
    {
        const float4* ap = reinterpret_cast<const float4*>(&aggS[(blk * 64 + l) * T_STEPS]);
        float4 a0 = ap[0], a1 = ap[1], a2 = ap[2];
        a_all[0] = a0.x; a_all[1] = a0.y; a_all[2]  = a0.z; a_all[3]  = a0.w;
        a_all[4] = a1.x; a_all[5] = a1.y; a_all[6]  = a1.z; a_all[7]  = a1.w;
        a_all[8] = a2.x; a_all[9] = a2.y; a_all[10] = a2.z; a_all[11] = a2.w;
    }

    float h_c[4][4];
#pragma unroll
    for (int mt = 0; mt < 4; mt++)
#pragma unroll
        for (int r = 0; r < 4; r++) h_c[mt][r] = 0.0f;
    {   // zero hlds[0] (h_0), 2 b128 stores/thread
        short8 z = (short8){0,0,0,0,0,0,0,0};
        *(short8*)&hlds[0][l * 64 + ((2 * w) << 3)]     = z;
        *(short8*)&hlds[0][l * 64 + ((2 * w + 1) << 3)] = z;
    }

#pragma unroll 1
    for (int t = 0; t < T_STEPS; t++) {
        const int p = t & 1;
        short* xw = xlds[p];
        const short* xr = xlds[p];
        const short* hr = hlds[p];
        short* hw = hlds[p ^ 1];

        // ---- X-stage: seq=l, k in [16wu,16wu+16), chunks 2w/2w+1, swizzled
        {
            const float a = a_all[t];
            float v[16];
#pragma unroll
            for (int j = 0; j < 16; j++) v[j] = fmaxf(fmaf(a, gwv[j], gbv[j]), 0.0f);
            uint4 q0 = { pk2bf(v[0], v[1]),  pk2bf(v[2], v[3]),
                         pk2bf(v[4], v[5]),  pk2bf(v[6], v[7]) };
            uint4 q1 = { pk2bf(v[8], v[9]),  pk2bf(v[10], v[11]),
                         pk2bf(v[12], v[13]), pk2bf(v[14], v[15]) };
            const int s3 = l & 7;
            *(uint4*)&xw[l * 64 + (((2 * w)     ^ s3) << 3)] = q0;
            *(uint4*)&xw[l * 64 + (((2 * w + 1) ^ s3) << 3)] = q1;
        }
        __syncthreads();   // X_t + h_{t-1} writes visible; separates same-parity reuse

        f32x4 accR[4], accZ[4], accNX[4], accNH[4];
#pragma unroll
        for (int mt = 0; mt < 4; mt++) {
            accR[mt]  = (f32x4){bR,  bR,  bR,  bR};
            accZ[mt]  = (f32x4){bZ,  bZ,  bZ,  bZ};
            accNX[mt] = (f32x4){bIN, bIN, bIN, bIN};
            accNH[mt] = (f32x4){bHN, bHN, bHN, bHN};
        }

#pragma unroll
        for (int mt = 0; mt < 4; mt++) {
            const int seq = mt * 16 + lr;
            const int s3 = seq & 7;
            short8 ax0 = *(const short8*)&xr[seq * 64 + (((0 + qu) ^ s3) << 3)];
            short8 ax1 = *(const short8*)&xr[seq * 64 + (((4 + qu) ^ s3) << 3)];
            short8 ah0 = *(const short8*)&hr[seq * 64 + (((0 + qu) ^ s3) << 3)];
            short8 ah1 = *(const short8*)&hr[seq * 64 + (((4 + qu) ^ s3) << 3)];

            accR[mt]  = __builtin_amdgcn_mfma_f32_16x16x32_bf16(ax0, bIr[0], accR[mt], 0, 0, 0);
            accR[mt]  = __builtin_amdgcn_mfma_f32_16x16x32_bf16(ax1, bIr[1], accR[mt], 0, 0, 0);
            accR[mt]  = __builtin_amdgcn_mfma_f32_16x16x32_bf16(ah0, bHr[0], accR[mt], 0, 0, 0);
            accR[mt]  = __builtin_amdgcn_mfma_f32_16x16x32_bf16(ah1, bHr[1], accR[mt], 0, 0, 0);
            accZ[mt]  = __builtin_amdgcn_mfma_f32_16x16x32_bf16(ax0, bIz[0], accZ[mt], 0, 0, 0);
            accZ[mt]  = __builtin_amdgcn_mfma_f32_16x16x32_bf16(ax1, bIz[1], accZ[mt], 0, 0, 0);
            accZ[mt]  = __builtin_amdgcn_mfma_f32_16x16x32_bf16(ah0, bHz[0], accZ[mt], 0, 0, 0);
            accZ[mt]  = __builtin_amdgcn_mfma_f32_16x16x32_bf16(ah1, bHz[1], accZ[mt], 0, 0, 0);
            accNX[mt] = __builtin_amdgcn_mfma_f32_16x16x32_bf16(ax0, bIn[0], accNX[mt], 0, 0, 0);
            accNX[mt] = __builtin_amdgcn_mfma_f32_16x16x32_bf16(ax1, bIn[1], accNX[mt], 0, 0, 0);
            accNH[mt] = __builtin_amdgcn_mfma_f32_16x16x32_bf16(ah0, bHn[0], accNH[mt], 0, 0, 0);
            accNH[mt] = __builtin_amdgcn_mfma_f32_16x16x32_bf16(ah1, bHn[1], accNH[mt], 0, 0, 0);
        }

        // gates -> write h_t into the OTHER h buffer (no second barrier needed)
#pragma unroll
        for (int mt = 0; mt < 4; mt++) {
            float hn_[4];
#pragma unroll
            for (int r = 0; r < 4; r++) {
                float pr = sigmoid_f(accR[mt][r]);
                float pz = sigmoid_f(accZ[mt][r]);
                float pn = tanh_f(fmaf(pr, accNH[mt][r], accNX[mt][r]));
                float hn = fmaf(pz, h_c[mt][r] - pn, pn);
                h_c[mt][r] = hn;
                hn_[r] = hn;
            }
#pragma unroll
            for (int r = 0; r < 4; r += 2) {
                unsigned pp = pk2bf(hn_[r], hn_[r + 1]);
                const int seq0 = mt * 16 + qu * 4 + r;
                const int seq1 = seq0 + 1;
                hw[seq0 * 64 + ((uc ^ (seq0 & 7)) << 3) + u7] = (short)(pp & 0xFFFFu);
                hw[seq1 * 64 + ((uc ^ (seq1 & 7)) << 3) + u7] = (short)(pp >> 16);
            }
        }
    }
    __syncthreads();   // final h (in hlds[0], T even) visible for head

    // ---- output head ----
    short8 bWo[2];
#pragma unroll
    for (int kt = 0; kt < 2; kt++)
        bWo[kt] = *(const short8*)&Woutb[lr * 64 + kt * 32 + qu * 8];
    const float bo = (lr < P_OUT) ? bout[lr] : 0.0f;

    f32x4 accO = (f32x4){0.f, 0.f, 0.f, 0.f};
    {
        const int seq = w * 16 + lr;
        const int s3 = seq & 7;
        short8 ah0 = *(const short8*)&hlds[0][seq * 64 + (((0 + qu) ^ s3) << 3)];
        short8 ah1 = *(const short8*)&hlds[0][seq * 64 + (((4 + qu) ^ s3) << 3)];
        accO = __builtin_amdgcn_mfma_f32_16x16x32_bf16(ah0, bWo[0], accO, 0, 0, 0);
        accO = __builtin_amdgcn_mfma_f32_16x16x32_bf16(ah1, bWo[1], accO, 0, 0, 0);
    }
    if (lr < P_OUT) {
#pragma unroll
        for (int r = 0; r < 4; r++) {
            const int seq = w * 16 + qu * 4 + r;
            out[(blk * 64 + seq) * P_OUT + lr] = accO[r] + bo;
        }
    }
}

// ---------------- launcher ----------------

extern "C" void kernel_launch(void* const* d_in, const int* in_sizes, int n_in,
                              void* d_out, int out_size, void* d_ws, size_t ws_size,
                              hipStream_t stream)
{
    const float* x    = (const float*)d_in[0];
    const int*   ei   = (const int*)  d_in[1];
    const float* ew   = (const float*)d_in[2];
    const float* gW   = (const float*)d_in[3];
    const float* gb   = (const float*)d_in[4];
    const float* Wih  = (const float*)d_in[5];
    const float* Whh  = (const float*)d_in[6];
    const float* bih  = (const float*)d_in[7];
    const float* bhh  = (const float*)d_in[8];
    const float* Wout = (const float*)d_in[9];
    const float* bout = (const float*)d_in[10];
    float* out = (float*)d_out;

    float* deg    = (float*)d_ws;                 // N
    int*   cnt    = (int*)(deg + N_NODES);        // N
    int*   cursor = cnt + N_NODES;                // N
    int*   off    = cursor + N_NODES;             // N
    int2*  csr    = (int2*)(off + N_NODES);       // E
    float* aggS   = (float*)(csr + E_EDGES);      // BN*12, layout [bn][12]
    short* Wihb   = (short*)(aggS + BN * T_STEPS);
    short* Whhb   = Wihb + 192 * 64;
    short* Woutb  = Whhb + 192 * 64;

    hipMemsetAsync(deg, 0, 3 * N_NODES * sizeof(float), stream);   // deg+cnt+cursor
    prep_kernel<<<673, 256, 0, stream>>>(ei, ew, deg, cnt, Wih, Whh, Wout,
                                         Wihb, Whhb, Woutb);
    scan_dinv_kernel<<<1, 256, 0, stream>>>(cnt, off, deg);
    fill_kernel<<<(E_EDGES + 255) / 256, 256, 0, stream>>>(ei, ew, deg, off, cursor, csr);
    gather_kernel<<<dim3(40, B, 3), 256, 0, stream>>>(x, deg, off, cnt, csr, aggS);
    gru_mfma_kernel<<<BN / 64, 256, 0, stream>>>(aggS, gW, gb, Wihb, Whhb,
                                                 bih, bhh, Woutb, bout, out);
}

// Round 8
// 207.310 us; speedup vs baseline: 1.1920x; 1.1920x over previous
//
#include <hip/hip_runtime.h>

#define N_NODES 10000
#define B 8
#define T_STEPS 12
#define E_EDGES 160000
#define HG 64
#define HR 64
#define P_OUT 12
#define BN (B * N_NODES)   // 80000
#define CAP 48             // per-node CSR bucket capacity (Poisson λ=16; P(>48)≈1e-11/node)

typedef __attribute__((ext_vector_type(8))) short short8;
typedef __attribute__((ext_vector_type(4))) float f32x4;

__device__ __forceinline__ short f2bf(float f) {
    unsigned u = __builtin_bit_cast(unsigned, f);
    u += 0x7FFFu + ((u >> 16) & 1u);     // round-to-nearest-even
    return (short)(u >> 16);
}

// ---------------- prep: degree histogram + weight cvt (fused) ----------------
// blocks [0,625): one thread per edge -> deg atomic (cnt no longer needed:
// fill's cursor doubles as the count).
// blocks [625,673): weight bf16 conversion.

__global__ void prep_kernel(const int* __restrict__ ei, const float* __restrict__ ew,
                            float* __restrict__ deg,
                            const float* __restrict__ Wih, const float* __restrict__ Whh,
                            const float* __restrict__ Wout,
                            short* __restrict__ Wihb, short* __restrict__ Whhb,
                            short* __restrict__ Woutb) {
    if (blockIdx.x < 625) {
        int e = blockIdx.x * 256 + threadIdx.x;          // 625*256 == E_EDGES
        atomicAdd(&deg[ei[E_EDGES + e]], ew[e]);
    } else {
        int i = (blockIdx.x - 625) * 256 + threadIdx.x;
        if (i < 192 * 64) {
            Wihb[i] = f2bf(Wih[i]);
            Whhb[i] = f2bf(Whh[i]);
        }
        if (i < 16 * 64) {
            int p = i >> 6, k = i & 63;
            Woutb[i] = (p < P_OUT) ? f2bf(Wout[p * 64 + k]) : (short)0;
        }
    }
}

// ---------------- dinv (parallel; replaces the single-block scan) ----------------
__global__ void dinv_kernel(float* __restrict__ deg) {
    int n = blockIdx.x * 256 + threadIdx.x;
    if (n < N_NODES) deg[n] = rsqrtf(deg[n] + 1.0f);   // +1 = self-loop weight
}

// ---------------- fill bucketed CSR (no scan needed) ----------------
__global__ void fill_kernel(const int* __restrict__ ei, const float* __restrict__ ew,
                            const float* __restrict__ dinv,
                            int* __restrict__ cursor, int2* __restrict__ csr) {
    int e = blockIdx.x * blockDim.x + threadIdx.x;
    if (e >= E_EDGES) return;
    int s = ei[e];
    int d = ei[E_EDGES + e];
    int pos = atomicAdd(&cursor[d], 1);
    if (pos < CAP)   // never taken for this dataset; OOB guard only
        csr[d * CAP + pos] = make_int2(s, __float_as_int(dinv[s] * ew[e] * dinv[d]));
}

// ---------------- gather: thread per (b, n, t-quarter) ----------------
__global__ void gather_kernel(const float* __restrict__ x, const float* __restrict__ dinv,
                              const int* __restrict__ cnt,   // = cursor after fill
                              const int2* __restrict__ csr, float* __restrict__ aggS) {
    int n = blockIdx.x * 256 + threadIdx.x;
    if (n >= N_NODES) return;
    const int b  = blockIdx.y;
    const int tq = blockIdx.z;
    const int fo = tq * 4;                     // float offset within the 12
    float di = dinv[n];
    float4 acc;
    {
        float4 xs = *(const float4*)&x[(b * N_NODES + n) * T_STEPS + fo];
        float w = di * di;
        acc = make_float4(w * xs.x, w * xs.y, w * xs.z, w * xs.w);
    }
    const int c = min(cnt[n], CAP);
    const int2* cp = &csr[n * CAP];
#pragma unroll 4
    for (int i = 0; i < c; i++) {
        int2 pr = cp[i];
        float w = __int_as_float(pr.y);
        float4 xv = *(const float4*)&x[(b * N_NODES + pr.x) * T_STEPS + fo];
        acc.x = fmaf(w, xv.x, acc.x);
        acc.y = fmaf(w, xv.y, acc.y);
        acc.z = fmaf(w, xv.z, acc.z);
        acc.w = fmaf(w, xv.w, acc.w);
    }
    *(float4*)&aggS[(b * N_NODES + n) * T_STEPS + fo] = acc;
}

// ---------------- Fused MFMA GRU + output head (exact R6 version, 82 µs) ----------------

__device__ __forceinline__ float fast_rcp(float v) { return __builtin_amdgcn_rcpf(v); }
__device__ __forceinline__ float sigmoid_f(float v) { return fast_rcp(1.0f + __expf(-v)); }
__device__ __forceinline__ float tanh_f(float v) {
    float e = __expf(-2.0f * v);
    return fmaf(2.0f, fast_rcp(1.0f + e), -1.0f);
}

__global__ __launch_bounds__(256, 2) void gru_mfma_kernel(
    const float* __restrict__ aggS,
    const float* __restrict__ gW, const float* __restrict__ gb,
    const short* __restrict__ Wihb, const short* __restrict__ Whhb,
    const float* __restrict__ bih, const float* __restrict__ bhh,
    const short* __restrict__ Woutb, const float* __restrict__ bout,
    float* __restrict__ out)
{
    __shared__ short hlds[64 * 64];   // 8 KB, row=seq, chunk c at slot (c ^ (seq&7))
    __shared__ short xlds[64 * 64];   // 8 KB, same swizzle
    const int tid = threadIdx.x;
    const int w   = tid >> 6;
    const int wu  = __builtin_amdgcn_readfirstlane(w);   // force wave-uniform (SGPR)
    const int l   = tid & 63;
    const int lr  = l & 15;
    const int qu  = l >> 4;
    const int blk = blockIdx.x;

    // t-invariant weight B-frags (pinned in registers)
    short8 bIr[2], bIz[2], bIn[2], bHr[2], bHz[2], bHn[2];
#pragma unroll
    for (int kt = 0; kt < 2; kt++) {
        const int ko = kt * 32 + qu * 8;
        bIr[kt] = *(const short8*)&Wihb[(      16 * wu + lr) * 64 + ko];
        bIz[kt] = *(const short8*)&Wihb[( 64 + 16 * wu + lr) * 64 + ko];
        bIn[kt] = *(const short8*)&Wihb[(128 + 16 * wu + lr) * 64 + ko];
        bHr[kt] = *(const short8*)&Whhb[(      16 * wu + lr) * 64 + ko];
        bHz[kt] = *(const short8*)&Whhb[( 64 + 16 * wu + lr) * 64 + ko];
        bHn[kt] = *(const short8*)&Whhb[(128 + 16 * wu + lr) * 64 + ko];
    }
    float gwv[16], gbv[16];
#pragma unroll
    for (int j = 0; j < 16; j++) { gwv[j] = gW[wu * 16 + j]; gbv[j] = gb[wu * 16 + j]; }

    const int u = 16 * w + lr;
    const float bR  = bih[u]       + bhh[u];
    const float bZ  = bih[u + 64]  + bhh[u + 64];
    const float bIN = bih[u + 128];
    const float bHN = bhh[u + 128];
    const int uc = u >> 3;
    const int u7 = u & 7;

    float a_all[12];
    {
        const float4* ap = reinterpret_cast<const float4*>(&aggS[(blk * 64 + l) * T_STEPS]);
        float4 a0 = ap[0], a1 = ap[1], a2 = ap[2];
        a_all[0] = a0.x; a_all[1] = a0.y; a_all[2]  = a0.z; a_all[3]  = a0.w;
        a_all[4] = a1.x; a_all[5] = a1.y; a_all[6]  = a1.z; a_all[7]  = a1.w;
        a_all[8] = a2.x; a_all[9] = a2.y; a_all[10] = a2.z; a_all[11] = a2.w;
    }

    float h_c[4][4];
#pragma unroll
    for (int mt = 0; mt < 4; mt++)
#pragma unroll
        for (int r = 0; r < 4; r++) h_c[mt][r] = 0.0f;
    {
        short8 z = (short8){0,0,0,0,0,0,0,0};
        *(short8*)&hlds[l * 64 + ((2 * w) << 3)]     = z;
        *(short8*)&hlds[l * 64 + ((2 * w + 1) << 3)] = z;
    }

#pragma unroll 1
    for (int t = 0; t < T_STEPS; t++) {
        // ---- X-stage: seq=l, k in [16wu,16wu+16), chunks 2w/2w+1, swizzled
        {
            const float a = a_all[t];
            short8 c0, c1;
#pragma unroll
            for (int j = 0; j < 8; j++) {
                c0[j] = f2bf(fmaxf(fmaf(a, gwv[j],     gbv[j]),     0.0f));
                c1[j] = f2bf(fmaxf(fmaf(a, gwv[8 + j], gbv[8 + j]), 0.0f));
            }
            const int s3 = l & 7;
            *(short8*)&xlds[l * 64 + (((2 * w)     ^ s3) << 3)] = c0;
            *(short8*)&xlds[l * 64 + (((2 * w + 1) ^ s3) << 3)] = c1;
        }
        __syncthreads();   // X_t + h_{t-1} visible

        f32x4 accR[4], accZ[4], accNX[4], accNH[4];
#pragma unroll
        for (int mt = 0; mt < 4; mt++) {
            accR[mt]  = (f32x4){bR,  bR,  bR,  bR};
            accZ[mt]  = (f32x4){bZ,  bZ,  bZ,  bZ};
            accNX[mt] = (f32x4){bIN, bIN, bIN, bIN};
            accNH[mt] = (f32x4){bHN, bHN, bHN, bHN};
        }

#pragma unroll
        for (int mt = 0; mt < 4; mt++) {
            const int seq = mt * 16 + lr;
            const int s3 = seq & 7;
            short8 ax0 = *(const short8*)&xlds[seq * 64 + (((0 + qu) ^ s3) << 3)];
            short8 ax1 = *(const short8*)&xlds[seq * 64 + (((4 + qu) ^ s3) << 3)];
            short8 ah0 = *(const short8*)&hlds[seq * 64 + (((0 + qu) ^ s3) << 3)];
            short8 ah1 = *(const short8*)&hlds[seq * 64 + (((4 + qu) ^ s3) << 3)];

            accR[mt]  = __builtin_amdgcn_mfma_f32_16x16x32_bf16(ax0, bIr[0], accR[mt], 0, 0, 0);
            accR[mt]  = __builtin_amdgcn_mfma_f32_16x16x32_bf16(ax1, bIr[1], accR[mt], 0, 0, 0);
            accR[mt]  = __builtin_amdgcn_mfma_f32_16x16x32_bf16(ah0, bHr[0], accR[mt], 0, 0, 0);
            accR[mt]  = __builtin_amdgcn_mfma_f32_16x16x32_bf16(ah1, bHr[1], accR[mt], 0, 0, 0);
            accZ[mt]  = __builtin_amdgcn_mfma_f32_16x16x32_bf16(ax0, bIz[0], accZ[mt], 0, 0, 0);
            accZ[mt]  = __builtin_amdgcn_mfma_f32_16x16x32_bf16(ax1, bIz[1], accZ[mt], 0, 0, 0);
            accZ[mt]  = __builtin_amdgcn_mfma_f32_16x16x32_bf16(ah0, bHz[0], accZ[mt], 0, 0, 0);
            accZ[mt]  = __builtin_amdgcn_mfma_f32_16x16x32_bf16(ah1, bHz[1], accZ[mt], 0, 0, 0);
            accNX[mt] = __builtin_amdgcn_mfma_f32_16x16x32_bf16(ax0, bIn[0], accNX[mt], 0, 0, 0);
            accNX[mt] = __builtin_amdgcn_mfma_f32_16x16x32_bf16(ax1, bIn[1], accNX[mt], 0, 0, 0);
            accNH[mt] = __builtin_amdgcn_mfma_f32_16x16x32_bf16(ah0, bHn[0], accNH[mt], 0, 0, 0);
            accNH[mt] = __builtin_amdgcn_mfma_f32_16x16x32_bf16(ah1, bHn[1], accNH[mt], 0, 0, 0);
        }
        __syncthreads();   // all A-frag reads complete

#pragma unroll
        for (int mt = 0; mt < 4; mt++) {
#pragma unroll
            for (int r = 0; r < 4; r++) {
                const int seq = mt * 16 + qu * 4 + r;
                float pr = sigmoid_f(accR[mt][r]);
                float pz = sigmoid_f(accZ[mt][r]);
                float pn = tanh_f(fmaf(pr, accNH[mt][r], accNX[mt][r]));
                float hn = fmaf(pz, h_c[mt][r] - pn, pn);
                h_c[mt][r] = hn;
                hlds[seq * 64 + ((uc ^ (seq & 7)) << 3) + u7] = f2bf(hn);
            }
        }
    }
    __syncthreads();   // final h visible for head

    // ---- output head ----
    short8 bWo[2];
#pragma unroll
    for (int kt = 0; kt < 2; kt++)
        bWo[kt] = *(const short8*)&Woutb[lr * 64 + kt * 32 + qu * 8];
    const float bo = (lr < P_OUT) ? bout[lr] : 0.0f;

    f32x4 accO = (f32x4){0.f, 0.f, 0.f, 0.f};
    {
        const int seq = w * 16 + lr;
        const int s3 = seq & 7;
        short8 ah0 = *(const short8*)&hlds[seq * 64 + (((0 + qu) ^ s3) << 3)];
        short8 ah1 = *(const short8*)&hlds[seq * 64 + (((4 + qu) ^ s3) << 3)];
        accO = __builtin_amdgcn_mfma_f32_16x16x32_bf16(ah0, bWo[0], accO, 0, 0, 0);
        accO = __builtin_amdgcn_mfma_f32_16x16x32_bf16(ah1, bWo[1], accO, 0, 0, 0);
    }
    if (lr < P_OUT) {
#pragma unroll
        for (int r = 0; r < 4; r++) {
            const int seq = w * 16 + qu * 4 + r;
            out[(blk * 64 + seq) * P_OUT + lr] = accO[r] + bo;
        }
    }
}

// ---------------- launcher ----------------

extern "C" void kernel_launch(void* const* d_in, const int* in_sizes, int n_in,
                              void* d_out, int out_size, void* d_ws, size_t ws_size,
                              hipStream_t stream)
{
    const float* x    = (const float*)d_in[0];
    const int*   ei   = (const int*)  d_in[1];
    const float* ew   = (const float*)d_in[2];
    const float* gW   = (const float*)d_in[3];
    const float* gb   = (const float*)d_in[4];
    const float* Wih  = (const float*)d_in[5];
    const float* Whh  = (const float*)d_in[6];
    const float* bih  = (const float*)d_in[7];
    const float* bhh  = (const float*)d_in[8];
    const float* Wout = (const float*)d_in[9];
    const float* bout = (const float*)d_in[10];
    float* out = (float*)d_out;

    float* deg    = (float*)d_ws;                 // N (becomes dinv in place)
    int*   cursor = (int*)(deg + N_NODES);        // N (doubles as per-node count)
    int2*  csr    = (int2*)(cursor + N_NODES);    // N*CAP buckets (8B-aligned: 80000B)
    float* aggS   = (float*)(csr + N_NODES * CAP);// BN*12, layout [bn][12]
    short* Wihb   = (short*)(aggS + BN * T_STEPS);
    short* Whhb   = Wihb + 192 * 64;
    short* Woutb  = Whhb + 192 * 64;

    hipMemsetAsync(deg, 0, 2 * N_NODES * sizeof(float), stream);   // deg + cursor
    prep_kernel<<<673, 256, 0, stream>>>(ei, ew, deg, Wih, Whh, Wout,
                                         Wihb, Whhb, Woutb);
    dinv_kernel<<<40, 256, 0, stream>>>(deg);
    fill_kernel<<<(E_EDGES + 255) / 256, 256, 0, stream>>>(ei, ew, deg, cursor, csr);
    gather_kernel<<<dim3(40, B, 3), 256, 0, stream>>>(x, deg, cursor, csr, aggS);
    gru_mfma_kernel<<<BN / 64, 256, 0, stream>>>(aggS, gW, gb, Wihb, Whhb,
                                                 bih, bhh, Woutb, bout, out);
}

// Round 9
// 196.009 us; speedup vs baseline: 1.2608x; 1.0577x over previous
//
#include <hip/hip_runtime.h>

#define N_NODES 10000
#define B 8
#define T_STEPS 12
#define E_EDGES 160000
#define HG 64
#define HR 64
#define P_OUT 12
#define BN (B * N_NODES)   // 80000
#define CAP 48             // per-node CSR bucket capacity (Poisson λ=16; P(>48)≈1e-11/node)

typedef __attribute__((ext_vector_type(8))) short short8;
typedef __attribute__((ext_vector_type(4))) float f32x4;

__device__ __forceinline__ short f2bf(float f) {
    unsigned u = __builtin_bit_cast(unsigned, f);
    u += 0x7FFFu + ((u >> 16) & 1u);     // round-to-nearest-even
    return (short)(u >> 16);
}

// ---------------- fillprep: deg atomic + bucket fill + weight cvt ----------------
// blocks [0,625): one thread per edge. Bucket stores RAW ew (normalization is
// recomputed at use from deg -> no dinv dependency -> one kernel, no scan).
// blocks [625,673): weight bf16 conversion.

__global__ void fillprep_kernel(const int* __restrict__ ei, const float* __restrict__ ew,
                                float* __restrict__ deg, int* __restrict__ cursor,
                                int2* __restrict__ csr,
                                const float* __restrict__ Wih, const float* __restrict__ Whh,
                                const float* __restrict__ Wout,
                                short* __restrict__ Wihb, short* __restrict__ Whhb,
                                short* __restrict__ Woutb) {
    if (blockIdx.x < 625) {
        int e = blockIdx.x * 256 + threadIdx.x;          // 625*256 == E_EDGES
        int s = ei[e];
        int d = ei[E_EDGES + e];
        float w = ew[e];
        atomicAdd(&deg[d], w);
        int pos = atomicAdd(&cursor[d], 1);
        if (pos < CAP)   // never taken for this dataset; OOB guard only
            csr[d * CAP + pos] = make_int2(s, __float_as_int(w));
    } else {
        int i = (blockIdx.x - 625) * 256 + threadIdx.x;
        if (i < 192 * 64) {
            Wihb[i] = f2bf(Wih[i]);
            Whhb[i] = f2bf(Whh[i]);
        }
        if (i < 16 * 64) {
            int p = i >> 6, k = i & 63;
            Woutb[i] = (p < P_OUT) ? f2bf(Wout[p * 64 + k]) : (short)0;
        }
    }
}

// ---------------- Fused gather + MFMA GRU + output head ----------------

__device__ __forceinline__ float fast_rcp(float v) { return __builtin_amdgcn_rcpf(v); }
__device__ __forceinline__ float sigmoid_f(float v) { return fast_rcp(1.0f + __expf(-v)); }
__device__ __forceinline__ float tanh_f(float v) {
    float e = __expf(-2.0f * v);
    return fmaf(2.0f, fast_rcp(1.0f + e), -1.0f);
}

// Block = 64 sequences, 4 waves; wave w owns gate-units [16w,16w+16).
// NEW vs R8: GCN gather fused into the prologue. Wave w gathers t in
// [3w,3w+3) for all 64 seqs (lane l = seq l) into a_sh[12][64]; dinv is
// recomputed inline as rsqrtf(deg+1) (bit-identical to the old dinv kernel,
// so norm = dinv[s]*ew*dinv[d] is unchanged). X-stage reads a_sh[t][l].
// Removes the standalone gather/dinv/fill-norm kernels AND the aggS
// round-trip; gather latency overlaps other blocks' MFMA.
__global__ __launch_bounds__(256, 2) void gru_mfma_kernel(
    const float* __restrict__ x, const float* __restrict__ deg,
    const int* __restrict__ cnt, const int2* __restrict__ csr,
    const float* __restrict__ gW, const float* __restrict__ gb,
    const short* __restrict__ Wihb, const short* __restrict__ Whhb,
    const float* __restrict__ bih, const float* __restrict__ bhh,
    const short* __restrict__ Woutb, const float* __restrict__ bout,
    float* __restrict__ out)
{
    __shared__ short hlds[64 * 64];    // 8 KB, row=seq, chunk c at slot (c ^ (seq&7))
    __shared__ short xlds[64 * 64];    // 8 KB, same swizzle
    __shared__ float a_sh[12][64];     // 3 KB, [t][seq]
    const int tid = threadIdx.x;
    const int w   = tid >> 6;
    const int wu  = __builtin_amdgcn_readfirstlane(w);   // force wave-uniform (SGPR)
    const int l   = tid & 63;
    const int lr  = l & 15;
    const int qu  = l >> 4;
    const int blk = blockIdx.x;

    // ---- fused GCN gather: wave wu covers t0..t0+2 for seq l ----
    {
        const int bn = blk * 64 + l;
        const int n  = bn % N_NODES;
        const int b  = bn / N_NODES;
        const int t0 = 3 * wu;
        const float di = rsqrtf(deg[n] + 1.0f);
        const float* xr = &x[(b * N_NODES + n) * T_STEPS + t0];
        float a0 = xr[0], a1 = xr[1], a2 = xr[2];
        const float w2 = di * di;
        a0 *= w2; a1 *= w2; a2 *= w2;
        const int c = min(cnt[n], CAP);
        const int2* cp = &csr[n * CAP];
#pragma unroll 4
        for (int i = 0; i < c; i++) {
            int2 pr = cp[i];
            float we = __int_as_float(pr.y) * rsqrtf(deg[pr.x] + 1.0f) * di;
            const float* xs = &x[(b * N_NODES + pr.x) * T_STEPS + t0];
            a0 = fmaf(we, xs[0], a0);
            a1 = fmaf(we, xs[1], a1);
            a2 = fmaf(we, xs[2], a2);
        }
        a_sh[t0][l] = a0; a_sh[t0 + 1][l] = a1; a_sh[t0 + 2][l] = a2;
    }

    // t-invariant weight B-frags (pinned in registers)
    short8 bIr[2], bIz[2], bIn[2], bHr[2], bHz[2], bHn[2];
#pragma unroll
    for (int kt = 0; kt < 2; kt++) {
        const int ko = kt * 32 + qu * 8;
        bIr[kt] = *(const short8*)&Wihb[(      16 * wu + lr) * 64 + ko];
        bIz[kt] = *(const short8*)&Wihb[( 64 + 16 * wu + lr) * 64 + ko];
        bIn[kt] = *(const short8*)&Wihb[(128 + 16 * wu + lr) * 64 + ko];
        bHr[kt] = *(const short8*)&Whhb[(      16 * wu + lr) * 64 + ko];
        bHz[kt] = *(const short8*)&Whhb[( 64 + 16 * wu + lr) * 64 + ko];
        bHn[kt] = *(const short8*)&Whhb[(128 + 16 * wu + lr) * 64 + ko];
    }
    float gwv[16], gbv[16];
#pragma unroll
    for (int j = 0; j < 16; j++) { gwv[j] = gW[wu * 16 + j]; gbv[j] = gb[wu * 16 + j]; }

    const int u = 16 * w + lr;
    const float bR  = bih[u]       + bhh[u];
    const float bZ  = bih[u + 64]  + bhh[u + 64];
    const float bIN = bih[u + 128];
    const float bHN = bhh[u + 128];
    const int uc = u >> 3;
    const int u7 = u & 7;

    float h_c[4][4];
#pragma unroll
    for (int mt = 0; mt < 4; mt++)
#pragma unroll
        for (int r = 0; r < 4; r++) h_c[mt][r] = 0.0f;
    {
        short8 z = (short8){0,0,0,0,0,0,0,0};
        *(short8*)&hlds[l * 64 + ((2 * w) << 3)]     = z;
        *(short8*)&hlds[l * 64 + ((2 * w + 1) << 3)] = z;
    }
    __syncthreads();   // a_sh + hlds zero visible to all waves

#pragma unroll 1
    for (int t = 0; t < T_STEPS; t++) {
        // ---- X-stage: seq=l, k in [16wu,16wu+16), chunks 2w/2w+1, swizzled
        {
            const float a = a_sh[t][l];
            short8 c0, c1;
#pragma unroll
            for (int j = 0; j < 8; j++) {
                c0[j] = f2bf(fmaxf(fmaf(a, gwv[j],     gbv[j]),     0.0f));
                c1[j] = f2bf(fmaxf(fmaf(a, gwv[8 + j], gbv[8 + j]), 0.0f));
            }
            const int s3 = l & 7;
            *(short8*)&xlds[l * 64 + (((2 * w)     ^ s3) << 3)] = c0;
            *(short8*)&xlds[l * 64 + (((2 * w + 1) ^ s3) << 3)] = c1;
        }
        __syncthreads();   // X_t + h_{t-1} visible

        f32x4 accR[4], accZ[4], accNX[4], accNH[4];
#pragma unroll
        for (int mt = 0; mt < 4; mt++) {
            accR[mt]  = (f32x4){bR,  bR,  bR,  bR};
            accZ[mt]  = (f32x4){bZ,  bZ,  bZ,  bZ};
            accNX[mt] = (f32x4){bIN, bIN, bIN, bIN};
            accNH[mt] = (f32x4){bHN, bHN, bHN, bHN};
        }

#pragma unroll
        for (int mt = 0; mt < 4; mt++) {
            const int seq = mt * 16 + lr;
            const int s3 = seq & 7;
            short8 ax0 = *(const short8*)&xlds[seq * 64 + (((0 + qu) ^ s3) << 3)];
            short8 ax1 = *(const short8*)&xlds[seq * 64 + (((4 + qu) ^ s3) << 3)];
            short8 ah0 = *(const short8*)&hlds[seq * 64 + (((0 + qu) ^ s3) << 3)];
            short8 ah1 = *(const short8*)&hlds[seq * 64 + (((4 + qu) ^ s3) << 3)];

            accR[mt]  = __builtin_amdgcn_mfma_f32_16x16x32_bf16(ax0, bIr[0], accR[mt], 0, 0, 0);
            accR[mt]  = __builtin_amdgcn_mfma_f32_16x16x32_bf16(ax1, bIr[1], accR[mt], 0, 0, 0);
            accR[mt]  = __builtin_amdgcn_mfma_f32_16x16x32_bf16(ah0, bHr[0], accR[mt], 0, 0, 0);
            accR[mt]  = __builtin_amdgcn_mfma_f32_16x16x32_bf16(ah1, bHr[1], accR[mt], 0, 0, 0);
            accZ[mt]  = __builtin_amdgcn_mfma_f32_16x16x32_bf16(ax0, bIz[0], accZ[mt], 0, 0, 0);
            accZ[mt]  = __builtin_amdgcn_mfma_f32_16x16x32_bf16(ax1, bIz[1], accZ[mt], 0, 0, 0);
            accZ[mt]  = __builtin_amdgcn_mfma_f32_16x16x32_bf16(ah0, bHz[0], accZ[mt], 0, 0, 0);
            accZ[mt]  = __builtin_amdgcn_mfma_f32_16x16x32_bf16(ah1, bHz[1], accZ[mt], 0, 0, 0);
            accNX[mt] = __builtin_amdgcn_mfma_f32_16x16x32_bf16(ax0, bIn[0], accNX[mt], 0, 0, 0);
            accNX[mt] = __builtin_amdgcn_mfma_f32_16x16x32_bf16(ax1, bIn[1], accNX[mt], 0, 0, 0);
            accNH[mt] = __builtin_amdgcn_mfma_f32_16x16x32_bf16(ah0, bHn[0], accNH[mt], 0, 0, 0);
            accNH[mt] = __builtin_amdgcn_mfma_f32_16x16x32_bf16(ah1, bHn[1], accNH[mt], 0, 0, 0);
        }
        __syncthreads();   // all A-frag reads complete

#pragma unroll
        for (int mt = 0; mt < 4; mt++) {
#pragma unroll
            for (int r = 0; r < 4; r++) {
                const int seq = mt * 16 + qu * 4 + r;
                float pr = sigmoid_f(accR[mt][r]);
                float pz = sigmoid_f(accZ[mt][r]);
                float pn = tanh_f(fmaf(pr, accNH[mt][r], accNX[mt][r]));
                float hn = fmaf(pz, h_c[mt][r] - pn, pn);
                h_c[mt][r] = hn;
                hlds[seq * 64 + ((uc ^ (seq & 7)) << 3) + u7] = f2bf(hn);
            }
        }
    }
    __syncthreads();   // final h visible for head

    // ---- output head ----
    short8 bWo[2];
#pragma unroll
    for (int kt = 0; kt < 2; kt++)
        bWo[kt] = *(const short8*)&Woutb[lr * 64 + kt * 32 + qu * 8];
    const float bo = (lr < P_OUT) ? bout[lr] : 0.0f;

    f32x4 accO = (f32x4){0.f, 0.f, 0.f, 0.f};
    {
        const int seq = w * 16 + lr;
        const int s3 = seq & 7;
        short8 ah0 = *(const short8*)&hlds[seq * 64 + (((0 + qu) ^ s3) << 3)];
        short8 ah1 = *(const short8*)&hlds[seq * 64 + (((4 + qu) ^ s3) << 3)];
        accO = __builtin_amdgcn_mfma_f32_16x16x32_bf16(ah0, bWo[0], accO, 0, 0, 0);
        accO = __builtin_amdgcn_mfma_f32_16x16x32_bf16(ah1, bWo[1], accO, 0, 0, 0);
    }
    if (lr < P_OUT) {
#pragma unroll
        for (int r = 0; r < 4; r++) {
            const int seq = w * 16 + qu * 4 + r;
            out[(blk * 64 + seq) * P_OUT + lr] = accO[r] + bo;
        }
    }
}

// ---------------- launcher: 3 graph nodes ----------------

extern "C" void kernel_launch(void* const* d_in, const int* in_sizes, int n_in,
                              void* d_out, int out_size, void* d_ws, size_t ws_size,
                              hipStream_t stream)
{
    const float* x    = (const float*)d_in[0];
    const int*   ei   = (const int*)  d_in[1];
    const float* ew   = (const float*)d_in[2];
    const float* gW   = (const float*)d_in[3];
    const float* gb   = (const float*)d_in[4];
    const float* Wih  = (const float*)d_in[5];
    const float* Whh  = (const float*)d_in[6];
    const float* bih  = (const float*)d_in[7];
    const float* bhh  = (const float*)d_in[8];
    const float* Wout = (const float*)d_in[9];
    const float* bout = (const float*)d_in[10];
    float* out = (float*)d_out;

    float* deg    = (float*)d_ws;                 // N (raw degree; rsqrt at use)
    int*   cursor = (int*)(deg + N_NODES);        // N (doubles as per-node count)
    int2*  csr    = (int2*)(cursor + N_NODES);    // N*CAP buckets: (src, raw ew)
    short* Wihb   = (short*)(csr + N_NODES * CAP);
    short* Whhb   = Wihb + 192 * 64;
    short* Woutb  = Whhb + 192 * 64;

    hipMemsetAsync(deg, 0, 2 * N_NODES * sizeof(float), stream);   // deg + cursor
    fillprep_kernel<<<673, 256, 0, stream>>>(ei, ew, deg, cursor, csr,
                                             Wih, Whh, Wout, Wihb, Whhb, Woutb);
    gru_mfma_kernel<<<BN / 64, 256, 0, stream>>>(x, deg, cursor, csr, gW, gb,
                                                 Wihb, Whhb, bih, bhh,
                                                 Woutb, bout, out);
}

// Round 10
// 178.647 us; speedup vs baseline: 1.3833x; 1.0972x over previous
//
#include <hip/hip_runtime.h>

#define N_NODES 10000
#define B 8
#define T_STEPS 12
#define E_EDGES 160000
#define HG 64
#define HR 64
#define P_OUT 12
#define BN (B * N_NODES)   // 80000
#define CAP 48             // per-node CSR bucket capacity (Poisson λ=16; P(>48)≈1e-11/node)

typedef __attribute__((ext_vector_type(8))) short short8;
typedef __attribute__((ext_vector_type(4))) float f32x4;

__device__ __forceinline__ short f2bf(float f) {
    unsigned u = __builtin_bit_cast(unsigned, f);
    u += 0x7FFFu + ((u >> 16) & 1u);     // round-to-nearest-even
    return (short)(u >> 16);
}

// ---------------- fillprep: deg atomic + bucket fill + weight cvt ----------------
// blocks [0,625): one thread per edge. Bucket stores RAW ew (normalization is
// recomputed at use from deg -> no dinv dependency -> one kernel, no scan).
// blocks [625,673): weight bf16 conversion.

__global__ void fillprep_kernel(const int* __restrict__ ei, const float* __restrict__ ew,
                                float* __restrict__ deg, int* __restrict__ cursor,
                                int2* __restrict__ csr,
                                const float* __restrict__ Wih, const float* __restrict__ Whh,
                                const float* __restrict__ Wout,
                                short* __restrict__ Wihb, short* __restrict__ Whhb,
                                short* __restrict__ Woutb) {
    if (blockIdx.x < 625) {
        int e = blockIdx.x * 256 + threadIdx.x;          // 625*256 == E_EDGES
        int s = ei[e];
        int d = ei[E_EDGES + e];
        float w = ew[e];
        atomicAdd(&deg[d], w);
        int pos = atomicAdd(&cursor[d], 1);
        if (pos < CAP)   // never taken for this dataset; OOB guard only
            csr[d * CAP + pos] = make_int2(s, __float_as_int(w));
    } else {
        int i = (blockIdx.x - 625) * 256 + threadIdx.x;
        if (i < 192 * 64) {
            Wihb[i] = f2bf(Wih[i]);
            Whhb[i] = f2bf(Whh[i]);
        }
        if (i < 16 * 64) {
            int p = i >> 6, k = i & 63;
            Woutb[i] = (p < P_OUT) ? f2bf(Wout[p * 64 + k]) : (short)0;
        }
    }
}

// ---------------- Fused gather + MFMA GRU + output head ----------------

__device__ __forceinline__ float fast_rcp(float v) { return __builtin_amdgcn_rcpf(v); }
__device__ __forceinline__ float sigmoid_f(float v) { return fast_rcp(1.0f + __expf(-v)); }
__device__ __forceinline__ float tanh_f(float v) {
    float e = __expf(-2.0f * v);
    return fmaf(2.0f, fast_rcp(1.0f + e), -1.0f);
}

// Block = 64 sequences, 4 waves; wave w owns gate-units [16w,16w+16).
// R10 gather: 4-lane-cooperative. Wave w covers seqs [16w,16w+16); the 4
// sublanes of each seq split its edge list (i = sub, sub+4, ...), each
// accumulating ALL 12 t's from the aligned 48B x-row (3x float4). A 2-step
// shfl_xor butterfly (masks 1,2) reduces across sublanes; sublane 0 applies
// a = di*(sum + di*x[n]) and writes a_sh[12][64]. vs R9: csr reads & per-edge
// rsqrt 1x (was 4x), latency tail /4, aligned vector x loads.
__global__ __launch_bounds__(256, 2) void gru_mfma_kernel(
    const float* __restrict__ x, const float* __restrict__ deg,
    const int* __restrict__ cnt, const int2* __restrict__ csr,
    const float* __restrict__ gW, const float* __restrict__ gb,
    const short* __restrict__ Wihb, const short* __restrict__ Whhb,
    const float* __restrict__ bih, const float* __restrict__ bhh,
    const short* __restrict__ Woutb, const float* __restrict__ bout,
    float* __restrict__ out)
{
    __shared__ short hlds[64 * 64];    // 8 KB, row=seq, chunk c at slot (c ^ (seq&7))
    __shared__ short xlds[64 * 64];    // 8 KB, same swizzle
    __shared__ float a_sh[12][64];     // 3 KB, [t][seq]
    const int tid = threadIdx.x;
    const int w   = tid >> 6;
    const int wu  = __builtin_amdgcn_readfirstlane(w);   // force wave-uniform (SGPR)
    const int l   = tid & 63;
    const int lr  = l & 15;
    const int qu  = l >> 4;
    const int blk = blockIdx.x;

    // ---- cooperative GCN gather ----
    {
        const int sub = l & 3;                // sublane within 4-lane group
        const int seq = wu * 16 + (l >> 2);   // this group's sequence
        const int bn  = blk * 64 + seq;
        const int n   = bn % N_NODES;
        const int b   = bn / N_NODES;
        const float di = rsqrtf(deg[n] + 1.0f);
        float4 A0 = {0.f,0.f,0.f,0.f}, A1 = {0.f,0.f,0.f,0.f}, A2 = {0.f,0.f,0.f,0.f};
        const int c = min(cnt[n], CAP);
        const int2* cp = &csr[n * CAP];
#pragma unroll 2
        for (int i = sub; i < c; i += 4) {
            int2 pr = cp[i];
            float we = __int_as_float(pr.y) * rsqrtf(deg[pr.x] + 1.0f);  // di factored out
            const float4* xs = (const float4*)&x[(b * N_NODES + pr.x) * T_STEPS];
            float4 x0 = xs[0], x1 = xs[1], x2 = xs[2];
            A0.x = fmaf(we, x0.x, A0.x); A0.y = fmaf(we, x0.y, A0.y);
            A0.z = fmaf(we, x0.z, A0.z); A0.w = fmaf(we, x0.w, A0.w);
            A1.x = fmaf(we, x1.x, A1.x); A1.y = fmaf(we, x1.y, A1.y);
            A1.z = fmaf(we, x1.z, A1.z); A1.w = fmaf(we, x1.w, A1.w);
            A2.x = fmaf(we, x2.x, A2.x); A2.y = fmaf(we, x2.y, A2.y);
            A2.z = fmaf(we, x2.z, A2.z); A2.w = fmaf(we, x2.w, A2.w);
        }
#pragma unroll
        for (int m = 1; m <= 2; m <<= 1) {
            A0.x += __shfl_xor(A0.x, m); A0.y += __shfl_xor(A0.y, m);
            A0.z += __shfl_xor(A0.z, m); A0.w += __shfl_xor(A0.w, m);
            A1.x += __shfl_xor(A1.x, m); A1.y += __shfl_xor(A1.y, m);
            A1.z += __shfl_xor(A1.z, m); A1.w += __shfl_xor(A1.w, m);
            A2.x += __shfl_xor(A2.x, m); A2.y += __shfl_xor(A2.y, m);
            A2.z += __shfl_xor(A2.z, m); A2.w += __shfl_xor(A2.w, m);
        }
        if (sub == 0) {
            const float4* xn = (const float4*)&x[(b * N_NODES + n) * T_STEPS];
            float4 x0 = xn[0], x1 = xn[1], x2 = xn[2];
            a_sh[0][seq]  = di * fmaf(di, x0.x, A0.x);
            a_sh[1][seq]  = di * fmaf(di, x0.y, A0.y);
            a_sh[2][seq]  = di * fmaf(di, x0.z, A0.z);
            a_sh[3][seq]  = di * fmaf(di, x0.w, A0.w);
            a_sh[4][seq]  = di * fmaf(di, x1.x, A1.x);
            a_sh[5][seq]  = di * fmaf(di, x1.y, A1.y);
            a_sh[6][seq]  = di * fmaf(di, x1.z, A1.z);
            a_sh[7][seq]  = di * fmaf(di, x1.w, A1.w);
            a_sh[8][seq]  = di * fmaf(di, x2.x, A2.x);
            a_sh[9][seq]  = di * fmaf(di, x2.y, A2.y);
            a_sh[10][seq] = di * fmaf(di, x2.z, A2.z);
            a_sh[11][seq] = di * fmaf(di, x2.w, A2.w);
        }
    }

    // t-invariant weight B-frags (pinned in registers)
    short8 bIr[2], bIz[2], bIn[2], bHr[2], bHz[2], bHn[2];
#pragma unroll
    for (int kt = 0; kt < 2; kt++) {
        const int ko = kt * 32 + qu * 8;
        bIr[kt] = *(const short8*)&Wihb[(      16 * wu + lr) * 64 + ko];
        bIz[kt] = *(const short8*)&Wihb[( 64 + 16 * wu + lr) * 64 + ko];
        bIn[kt] = *(const short8*)&Wihb[(128 + 16 * wu + lr) * 64 + ko];
        bHr[kt] = *(const short8*)&Whhb[(      16 * wu + lr) * 64 + ko];
        bHz[kt] = *(const short8*)&Whhb[( 64 + 16 * wu + lr) * 64 + ko];
        bHn[kt] = *(const short8*)&Whhb[(128 + 16 * wu + lr) * 64 + ko];
    }
    float gwv[16], gbv[16];
#pragma unroll
    for (int j = 0; j < 16; j++) { gwv[j] = gW[wu * 16 + j]; gbv[j] = gb[wu * 16 + j]; }

    const int u = 16 * w + lr;
    const float bR  = bih[u]       + bhh[u];
    const float bZ  = bih[u + 64]  + bhh[u + 64];
    const float bIN = bih[u + 128];
    const float bHN = bhh[u + 128];
    const int uc = u >> 3;
    const int u7 = u & 7;

    float h_c[4][4];
#pragma unroll
    for (int mt = 0; mt < 4; mt++)
#pragma unroll
        for (int r = 0; r < 4; r++) h_c[mt][r] = 0.0f;
    {
        short8 z = (short8){0,0,0,0,0,0,0,0};
        *(short8*)&hlds[l * 64 + ((2 * w) << 3)]     = z;
        *(short8*)&hlds[l * 64 + ((2 * w + 1) << 3)] = z;
    }
    __syncthreads();   // a_sh + hlds zero visible to all waves

#pragma unroll 1
    for (int t = 0; t < T_STEPS; t++) {
        // ---- X-stage: seq=l, k in [16wu,16wu+16), chunks 2w/2w+1, swizzled
        {
            const float a = a_sh[t][l];
            short8 c0, c1;
#pragma unroll
            for (int j = 0; j < 8; j++) {
                c0[j] = f2bf(fmaxf(fmaf(a, gwv[j],     gbv[j]),     0.0f));
                c1[j] = f2bf(fmaxf(fmaf(a, gwv[8 + j], gbv[8 + j]), 0.0f));
            }
            const int s3 = l & 7;
            *(short8*)&xlds[l * 64 + (((2 * w)     ^ s3) << 3)] = c0;
            *(short8*)&xlds[l * 64 + (((2 * w + 1) ^ s3) << 3)] = c1;
        }
        __syncthreads();   // X_t + h_{t-1} visible

        f32x4 accR[4], accZ[4], accNX[4], accNH[4];
#pragma unroll
        for (int mt = 0; mt < 4; mt++) {
            accR[mt]  = (f32x4){bR,  bR,  bR,  bR};
            accZ[mt]  = (f32x4){bZ,  bZ,  bZ,  bZ};
            accNX[mt] = (f32x4){bIN, bIN, bIN, bIN};
            accNH[mt] = (f32x4){bHN, bHN, bHN, bHN};
        }

#pragma unroll
        for (int mt = 0; mt < 4; mt++) {
            const int seq = mt * 16 + lr;
            const int s3 = seq & 7;
            short8 ax0 = *(const short8*)&xlds[seq * 64 + (((0 + qu) ^ s3) << 3)];
            short8 ax1 = *(const short8*)&xlds[seq * 64 + (((4 + qu) ^ s3) << 3)];
            short8 ah0 = *(const short8*)&hlds[seq * 64 + (((0 + qu) ^ s3) << 3)];
            short8 ah1 = *(const short8*)&hlds[seq * 64 + (((4 + qu) ^ s3) << 3)];

            accR[mt]  = __builtin_amdgcn_mfma_f32_16x16x32_bf16(ax0, bIr[0], accR[mt], 0, 0, 0);
            accR[mt]  = __builtin_amdgcn_mfma_f32_16x16x32_bf16(ax1, bIr[1], accR[mt], 0, 0, 0);
            accR[mt]  = __builtin_amdgcn_mfma_f32_16x16x32_bf16(ah0, bHr[0], accR[mt], 0, 0, 0);
            accR[mt]  = __builtin_amdgcn_mfma_f32_16x16x32_bf16(ah1, bHr[1], accR[mt], 0, 0, 0);
            accZ[mt]  = __builtin_amdgcn_mfma_f32_16x16x32_bf16(ax0, bIz[0], accZ[mt], 0, 0, 0);
            accZ[mt]  = __builtin_amdgcn_mfma_f32_16x16x32_bf16(ax1, bIz[1], accZ[mt], 0, 0, 0);
            accZ[mt]  = __builtin_amdgcn_mfma_f32_16x16x32_bf16(ah0, bHz[0], accZ[mt], 0, 0, 0);
            accZ[mt]  = __builtin_amdgcn_mfma_f32_16x16x32_bf16(ah1, bHz[1], accZ[mt], 0, 0, 0);
            accNX[mt] = __builtin_amdgcn_mfma_f32_16x16x32_bf16(ax0, bIn[0], accNX[mt], 0, 0, 0);
            accNX[mt] = __builtin_amdgcn_mfma_f32_16x16x32_bf16(ax1, bIn[1], accNX[mt], 0, 0, 0);
            accNH[mt] = __builtin_amdgcn_mfma_f32_16x16x32_bf16(ah0, bHn[0], accNH[mt], 0, 0, 0);
            accNH[mt] = __builtin_amdgcn_mfma_f32_16x16x32_bf16(ah1, bHn[1], accNH[mt], 0, 0, 0);
        }
        __syncthreads();   // all A-frag reads complete

#pragma unroll
        for (int mt = 0; mt < 4; mt++) {
#pragma unroll
            for (int r = 0; r < 4; r++) {
                const int seq = mt * 16 + qu * 4 + r;
                float pr = sigmoid_f(accR[mt][r]);
                float pz = sigmoid_f(accZ[mt][r]);
                float pn = tanh_f(fmaf(pr, accNH[mt][r], accNX[mt][r]));
                float hn = fmaf(pz, h_c[mt][r] - pn, pn);
                h_c[mt][r] = hn;
                hlds[seq * 64 + ((uc ^ (seq & 7)) << 3) + u7] = f2bf(hn);
            }
        }
    }
    __syncthreads();   // final h visible for head

    // ---- output head ----
    short8 bWo[2];
#pragma unroll
    for (int kt = 0; kt < 2; kt++)
        bWo[kt] = *(const short8*)&Woutb[lr * 64 + kt * 32 + qu * 8];
    const float bo = (lr < P_OUT) ? bout[lr] : 0.0f;

    f32x4 accO = (f32x4){0.f, 0.f, 0.f, 0.f};
    {
        const int seq = w * 16 + lr;
        const int s3 = seq & 7;
        short8 ah0 = *(const short8*)&hlds[seq * 64 + (((0 + qu) ^ s3) << 3)];
        short8 ah1 = *(const short8*)&hlds[seq * 64 + (((4 + qu) ^ s3) << 3)];
        accO = __builtin_amdgcn_mfma_f32_16x16x32_bf16(ah0, bWo[0], accO, 0, 0, 0);
        accO = __builtin_amdgcn_mfma_f32_16x16x32_bf16(ah1, bWo[1], accO, 0, 0, 0);
    }
    if (lr < P_OUT) {
#pragma unroll
        for (int r = 0; r < 4; r++) {
            const int seq = w * 16 + qu * 4 + r;
            out[(blk * 64 + seq) * P_OUT + lr] = accO[r] + bo;
        }
    }
}

// ---------------- launcher: 3 graph nodes ----------------

extern "C" void kernel_launch(void* const* d_in, const int* in_sizes, int n_in,
                              void* d_out, int out_size, void* d_ws, size_t ws_size,
                              hipStream_t stream)
{
    const float* x    = (const float*)d_in[0];
    const int*   ei   = (const int*)  d_in[1];
    const float* ew   = (const float*)d_in[2];
    const float* gW   = (const float*)d_in[3];
    const float* gb   = (const float*)d_in[4];
    const float* Wih  = (const float*)d_in[5];
    const float* Whh  = (const float*)d_in[6];
    const float* bih  = (const float*)d_in[7];
    const float* bhh  = (const float*)d_in[8];
    const float* Wout = (const float*)d_in[9];
    const float* bout = (const float*)d_in[10];
    float* out = (float*)d_out;

    float* deg    = (float*)d_ws;                 // N (raw degree; rsqrt at use)
    int*   cursor = (int*)(deg + N_NODES);        // N (doubles as per-node count)
    int2*  csr    = (int2*)(cursor + N_NODES);    // N*CAP buckets: (src, raw ew)
    short* Wihb   = (short*)(csr + N_NODES * CAP);
    short* Whhb   = Wihb + 192 * 64;
    short* Woutb  = Whhb + 192 * 64;

    hipMemsetAsync(deg, 0, 2 * N_NODES * sizeof(float), stream);   // deg + cursor
    fillprep_kernel<<<673, 256, 0, stream>>>(ei, ew, deg, cursor, csr,
                                             Wih, Whh, Wout, Wihb, Whhb, Woutb);
    gru_mfma_kernel<<<BN / 64, 256, 0, stream>>>(x, deg, cursor, csr, gW, gb,
                                                 Wihb, Whhb, bih, bhh,
                                                 Woutb, bout, out);
}